// Round 1
// 7886.957 us; speedup vs baseline: 1.8246x; 1.8246x over previous
//
#include <hip/hip_runtime.h>
#include <hip/hip_bf16.h>
#include <math.h>

// ============================================================================
// GPT forward, B=2 T=2048 D=768 H=12 HD=64 L=4 V=32000.
// Round 2: flash-style tiled attention (64x64 tiles, LDS-staged K/V, online
// softmax). Old attn was ~8.6ms (60% of runtime): per-lane uncoalesced K-row
// gathers + serial PV loop + zero K/V reuse. New kernel reuses K/V across 64
// q-rows via LDS and computes both GEMMs with the 4x4-microtile pattern that
// already sustains ~76 TF in gemm_kernel. Everything else unchanged.
// ============================================================================

#define D_   768
#define T_   2048
#define NB_  4096   // B*T rows
#define HD_  64
#define NH_  12
#define NL_  4
#define V_   32000
#define EPS_ 1e-5f

// ---------------------------------------------------------------------------
// Embedding: x[row,:] = tok_emb[ids[row],:] + pos_emb[row % T,:]
// ---------------------------------------------------------------------------
__global__ __launch_bounds__(256) void embed_kernel(
    const int* __restrict__ ids, const float* __restrict__ tok,
    const float* __restrict__ pos, float* __restrict__ x) {
    int row = blockIdx.x;
    int t = row & (T_ - 1);
    int id = ids[row];
    const float* tr = tok + (size_t)id * D_;
    const float* pr = pos + (size_t)t * D_;
    float* xr = x + (size_t)row * D_;
    for (int i = threadIdx.x; i < D_; i += 256)
        xr[i] = tr[i] + pr[i];
}

// ---------------------------------------------------------------------------
// LayerNorm: one 256-thread block per row, D=768 -> 3 elems/thread
// ---------------------------------------------------------------------------
__global__ __launch_bounds__(256) void ln_kernel(
    const float* __restrict__ x, const float* __restrict__ g,
    const float* __restrict__ b, float* __restrict__ o) {
    int row = blockIdx.x, tid = threadIdx.x;
    const float* xr = x + (size_t)row * D_;
    float v0 = xr[tid], v1 = xr[tid + 256], v2 = xr[tid + 512];
    __shared__ float red[256];
    red[tid] = v0 + v1 + v2;
    __syncthreads();
    for (int off = 128; off > 0; off >>= 1) {
        if (tid < off) red[tid] += red[tid + off];
        __syncthreads();
    }
    float mu = red[0] * (1.0f / D_);
    __syncthreads();
    float d0 = v0 - mu, d1 = v1 - mu, d2 = v2 - mu;
    red[tid] = d0 * d0 + d1 * d1 + d2 * d2;
    __syncthreads();
    for (int off = 128; off > 0; off >>= 1) {
        if (tid < off) red[tid] += red[tid + off];
        __syncthreads();
    }
    float inv = rsqrtf(red[0] * (1.0f / D_) + EPS_);
    float* orow = o + (size_t)row * D_;
    orow[tid]       = d0 * inv * g[tid]       + b[tid];
    orow[tid + 256] = d1 * inv * g[tid + 256] + b[tid + 256];
    orow[tid + 512] = d2 * inv * g[tid + 512] + b[tid + 512];
}

// ---------------------------------------------------------------------------
// GEMM: C[M,N] = A[M,K] @ W[N,K]^T (+bias)(+gelu)(+residual)
// All fp32. 64x64 tile, BK=16, 256 threads, 4x4 per thread.
// ---------------------------------------------------------------------------
template <bool GELU>
__global__ __launch_bounds__(256) void gemm_kernel(
    const float* __restrict__ A, const float* __restrict__ W,
    const float* __restrict__ bias, const float* __restrict__ resid,
    float* __restrict__ C, int M, int N, int K) {
    // pad 68: row stride 272B (16B-multiple) so float4 LDS reads stay aligned
    __shared__ float As[16][68];
    __shared__ float Ws[16][68];
    int bn = blockIdx.x * 64, bm = blockIdx.y * 64;
    int tid = threadIdx.x;
    int tx = tid & 15, ty = tid >> 4;
    int lm = tid >> 2, lk = (tid & 3) << 2;
    float acc[4][4] = {{0.f}};
    const float* aPtr = A + (size_t)(bm + lm) * K + lk;
    const float* wPtr = W + (size_t)(bn + lm) * K + lk;
    for (int k0 = 0; k0 < K; k0 += 16) {
        float4 av = *(const float4*)(aPtr + k0);
        float4 wv = *(const float4*)(wPtr + k0);
        As[lk + 0][lm] = av.x; As[lk + 1][lm] = av.y;
        As[lk + 2][lm] = av.z; As[lk + 3][lm] = av.w;
        Ws[lk + 0][lm] = wv.x; Ws[lk + 1][lm] = wv.y;
        Ws[lk + 2][lm] = wv.z; Ws[lk + 3][lm] = wv.w;
        __syncthreads();
#pragma unroll
        for (int kk = 0; kk < 16; ++kk) {
            float4 ra = *(const float4*)&As[kk][ty * 4];
            float4 rb = *(const float4*)&Ws[kk][tx * 4];
            acc[0][0] += ra.x * rb.x; acc[0][1] += ra.x * rb.y;
            acc[0][2] += ra.x * rb.z; acc[0][3] += ra.x * rb.w;
            acc[1][0] += ra.y * rb.x; acc[1][1] += ra.y * rb.y;
            acc[1][2] += ra.y * rb.z; acc[1][3] += ra.y * rb.w;
            acc[2][0] += ra.z * rb.x; acc[2][1] += ra.z * rb.y;
            acc[2][2] += ra.z * rb.z; acc[2][3] += ra.z * rb.w;
            acc[3][0] += ra.w * rb.x; acc[3][1] += ra.w * rb.y;
            acc[3][2] += ra.w * rb.z; acc[3][3] += ra.w * rb.w;
        }
        __syncthreads();
    }
#pragma unroll
    for (int i = 0; i < 4; ++i) {
        int m = bm + ty * 4 + i;
#pragma unroll
        for (int j = 0; j < 4; ++j) {
            int n = bn + tx * 4 + j;
            float v = acc[i][j];
            if (bias) v += bias[n];
            if (GELU) v = 0.5f * v * (1.0f + erff(v * 0.70710678118654752f));
            if (resid) v += resid[(size_t)m * N + n];
            C[(size_t)m * N + n] = v;
        }
    }
}

// ---------------------------------------------------------------------------
// Flash-style causal attention.
// Block = 256 threads handles a 64-row q-tile for one (head, batch).
// Iterates k-tiles of 64 rows: S = Q.K^T (4x4 microtile GEMM over d=64),
// online softmax with 16-lane shuffle row-reductions, P.V accumulated into
// registers. Q/K staged transposed [d][idx] in LDS, V natural [k][d],
// P transposed [k][q]. LDS total ~70 KB -> 2 blocks/CU.
// qkv rows: [q(768) | k(768) | v(768)], head slice h*64..h*64+63.
// ---------------------------------------------------------------------------
__global__ __launch_bounds__(256) void flash_attn_kernel(
    const float* __restrict__ qkv, float* __restrict__ attout) {
    int qt = (T_ / 64 - 1) - blockIdx.x;  // reversed: heavy tiles launch first
    int h = blockIdx.y, b = blockIdx.z;
    int tid = threadIdx.x;
    int tx = tid & 15, ty = tid >> 4;

    __shared__ float Qs[64][68];  // [d][q]
    __shared__ float Ks[64][68];  // [d][k]
    __shared__ float Vs[64][68];  // [k][d]
    __shared__ float Ps[64][68];  // [k][q]

    const float* base = qkv + (size_t)b * T_ * 2304;
    int lr = tid >> 2, lc = (tid & 3) * 16;  // staging: 4 threads per row

    // ---- load Q tile (transposed into Qs[d][q]) ----
    {
        const float* qr = base + (size_t)(qt * 64 + lr) * 2304 + h * 64 + lc;
#pragma unroll
        for (int u = 0; u < 4; ++u) {
            float4 v = *(const float4*)(qr + u * 4);
            Qs[lc + u * 4 + 0][lr] = v.x;
            Qs[lc + u * 4 + 1][lr] = v.y;
            Qs[lc + u * 4 + 2][lr] = v.z;
            Qs[lc + u * 4 + 3][lr] = v.w;
        }
    }

    float m_i[4] = {-1e30f, -1e30f, -1e30f, -1e30f};
    float l_i[4] = {0.f, 0.f, 0.f, 0.f};
    float O[4][4] = {{0.f}};

    for (int kt = 0; kt <= qt; ++kt) {
        __syncthreads();  // prev gemm2 done reading Vs/Ps (also covers Q load)
        // ---- stage K (transposed) and V (natural) ----
        {
            const float* kr =
                base + (size_t)(kt * 64 + lr) * 2304 + 768 + h * 64 + lc;
#pragma unroll
            for (int u = 0; u < 4; ++u) {
                float4 kv = *(const float4*)(kr + u * 4);
                Ks[lc + u * 4 + 0][lr] = kv.x;
                Ks[lc + u * 4 + 1][lr] = kv.y;
                Ks[lc + u * 4 + 2][lr] = kv.z;
                Ks[lc + u * 4 + 3][lr] = kv.w;
                float4 vv = *(const float4*)(kr + 768 + u * 4);
                *(float4*)&Vs[lr][lc + u * 4] = vv;
            }
        }
        __syncthreads();

        // ---- S = Q.K^T (scaled), 4x4 microtile over d ----
        float s[4][4] = {{0.f}};
#pragma unroll 8
        for (int dd = 0; dd < 64; ++dd) {
            float4 ra = *(const float4*)&Qs[dd][ty * 4];
            float4 rb = *(const float4*)&Ks[dd][tx * 4];
            s[0][0] += ra.x * rb.x; s[0][1] += ra.x * rb.y;
            s[0][2] += ra.x * rb.z; s[0][3] += ra.x * rb.w;
            s[1][0] += ra.y * rb.x; s[1][1] += ra.y * rb.y;
            s[1][2] += ra.y * rb.z; s[1][3] += ra.y * rb.w;
            s[2][0] += ra.z * rb.x; s[2][1] += ra.z * rb.y;
            s[2][2] += ra.z * rb.z; s[2][3] += ra.z * rb.w;
            s[3][0] += ra.w * rb.x; s[3][1] += ra.w * rb.y;
            s[3][2] += ra.w * rb.z; s[3][3] += ra.w * rb.w;
        }
        const float scale = 0.125f;  // 1/sqrt(64)
#pragma unroll
        for (int i = 0; i < 4; ++i)
#pragma unroll
            for (int j = 0; j < 4; ++j) {
                float v = s[i][j] * scale;
                if (kt == qt && tx * 4 + j > ty * 4 + i) v = -1e30f;
                s[i][j] = v;
            }

        // ---- online softmax (rows spread over the 16 tx lanes, same-ty
        //      threads are 16 consecutive lanes -> shfl_xor group reduce) ----
#pragma unroll
        for (int i = 0; i < 4; ++i) {
            float pm = fmaxf(fmaxf(s[i][0], s[i][1]), fmaxf(s[i][2], s[i][3]));
#pragma unroll
            for (int off = 1; off < 16; off <<= 1)
                pm = fmaxf(pm, __shfl_xor(pm, off, 64));
            float mn = fmaxf(m_i[i], pm);
            float al = __expf(m_i[i] - mn);
            m_i[i] = mn;
            float ps = 0.f;
#pragma unroll
            for (int j = 0; j < 4; ++j) {
                float p = __expf(s[i][j] - mn);
                s[i][j] = p;
                ps += p;
            }
#pragma unroll
            for (int off = 1; off < 16; off <<= 1)
                ps += __shfl_xor(ps, off, 64);
            l_i[i] = l_i[i] * al + ps;
            O[i][0] *= al; O[i][1] *= al; O[i][2] *= al; O[i][3] *= al;
        }

        // ---- write P transposed [k][q] ----
#pragma unroll
        for (int i = 0; i < 4; ++i)
#pragma unroll
            for (int j = 0; j < 4; ++j)
                Ps[tx * 4 + j][ty * 4 + i] = s[i][j];
        __syncthreads();

        // ---- O += P.V, 4x4 microtile over k ----
#pragma unroll 8
        for (int kk = 0; kk < 64; ++kk) {
            float4 ra = *(const float4*)&Ps[kk][ty * 4];
            float4 rb = *(const float4*)&Vs[kk][tx * 4];
            O[0][0] += ra.x * rb.x; O[0][1] += ra.x * rb.y;
            O[0][2] += ra.x * rb.z; O[0][3] += ra.x * rb.w;
            O[1][0] += ra.y * rb.x; O[1][1] += ra.y * rb.y;
            O[1][2] += ra.y * rb.z; O[1][3] += ra.y * rb.w;
            O[2][0] += ra.z * rb.x; O[2][1] += ra.z * rb.y;
            O[2][2] += ra.z * rb.z; O[2][3] += ra.z * rb.w;
            O[3][0] += ra.w * rb.x; O[3][1] += ra.w * rb.y;
            O[3][2] += ra.w * rb.z; O[3][3] += ra.w * rb.w;
        }
    }

    // ---- normalize + store (coalesced float4 per row) ----
#pragma unroll
    for (int i = 0; i < 4; ++i) {
        int q = qt * 64 + ty * 4 + i;
        float inv = 1.0f / l_i[i];
        float4 o = make_float4(O[i][0] * inv, O[i][1] * inv, O[i][2] * inv,
                               O[i][3] * inv);
        *(float4*)&attout[((size_t)(b * T_ + q)) * D_ + h * 64 + tx * 4] = o;
    }
}

// ---------------------------------------------------------------------------
extern "C" void kernel_launch(void* const* d_in, const int* in_sizes, int n_in,
                              void* d_out, int out_size, void* d_ws,
                              size_t ws_size, hipStream_t stream) {
    const int*   ids  = (const int*)d_in[0];
    const float* tok  = (const float*)d_in[1];
    const float* pos  = (const float*)d_in[2];
    const float* ln1g = (const float*)d_in[3];
    const float* ln1b = (const float*)d_in[4];
    const float* Wqkv = (const float*)d_in[5];
    const float* bqkv = (const float*)d_in[6];
    const float* Wprj = (const float*)d_in[7];
    const float* bprj = (const float*)d_in[8];
    const float* ln2g = (const float*)d_in[9];
    const float* ln2b = (const float*)d_in[10];
    const float* W1   = (const float*)d_in[11];
    const float* b1   = (const float*)d_in[12];
    const float* W2   = (const float*)d_in[13];
    const float* b2   = (const float*)d_in[14];
    const float* lnfg = (const float*)d_in[15];
    const float* lnfb = (const float*)d_in[16];

    float* x   = (float*)d_ws;                  // 4096x768
    float* h   = x + (size_t)NB_ * D_;          // 4096x768
    float* qkv = h + (size_t)NB_ * D_;          // 4096x2304
    float* att = qkv + (size_t)NB_ * 3 * D_;    // 4096x768
    float* ff  = att + (size_t)NB_ * D_;        // 4096x3072

    embed_kernel<<<NB_, 256, 0, stream>>>(ids, tok, pos, x);

    for (int l = 0; l < NL_; ++l) {
        ln_kernel<<<NB_, 256, 0, stream>>>(x, ln1g + l * D_, ln1b + l * D_, h);
        gemm_kernel<false><<<dim3(2304 / 64, NB_ / 64), 256, 0, stream>>>(
            h, Wqkv + (size_t)l * 2304 * D_, bqkv + l * 2304, nullptr, qkv,
            NB_, 2304, D_);
        flash_attn_kernel<<<dim3(T_ / 64, NH_, 2), 256, 0, stream>>>(qkv, att);
        gemm_kernel<false><<<dim3(D_ / 64, NB_ / 64), 256, 0, stream>>>(
            att, Wprj + (size_t)l * D_ * D_, bprj + l * D_, x, x, NB_, D_, D_);
        ln_kernel<<<NB_, 256, 0, stream>>>(x, ln2g + l * D_, ln2b + l * D_, h);
        gemm_kernel<true><<<dim3(3072 / 64, NB_ / 64), 256, 0, stream>>>(
            h, W1 + (size_t)l * 3072 * D_, b1 + l * 3072, nullptr, ff,
            NB_, 3072, D_);
        gemm_kernel<false><<<dim3(D_ / 64, NB_ / 64), 256, 0, stream>>>(
            ff, W2 + (size_t)l * D_ * 3072, b2 + l * D_, x, x, NB_, D_, 3072);
    }

    ln_kernel<<<NB_, 256, 0, stream>>>(x, lnfg, lnfb, h);
    gemm_kernel<false><<<dim3(V_ / 64, NB_ / 64), 256, 0, stream>>>(
        h, tok, nullptr, nullptr, (float*)d_out, NB_, V_, D_);
}